// Round 5
// baseline (211.004 us; speedup 1.0000x reference)
//
#include <hip/hip_runtime.h>
#include <math.h>

#define T_IN        480000
#define OUT_PER_ROW 432000
#define K_TOT       48000      // output 9-groups per row
#define BLK         1024       // threads per block (16 waves)
#define GPB         816        // k-groups per block
#define LIN_FLOATS  8192       // staged input floats (covers 10*816+13+align)
#define LOUT_FLOATS (GPB * 9)  // 7344 staged outputs

struct ResampleW { float w[9][14]; };

__global__ __launch_bounds__(1024, 8)
void SpeedPerturb_resample_kernel(const float* __restrict__ in,
                                  float* __restrict__ out,
                                  ResampleW args)
{
    __shared__ float lin[LIN_FLOATS];
    __shared__ float lout[LOUT_FLOATS];
    const int row = blockIdx.y;
    const int k0  = blockIdx.x * GPB;
    const int t   = threadIdx.x;
    const int is0 = 10 * k0 - 6;          // first needed input index
    const int al  = is0 - 2;              // is0 % 4 == 2 always -> 16B-aligned base
    const float* rin = in + (size_t)row * T_IN;

    // ---- Stage 8192 floats: 2 independent float4 loads/thread -> regs,
    // ---- then LDS writes (keeps both misses in flight; no serial chain).
    const int g0 = al + 4 * t;            // first float4
    const int g1 = g0 + 4 * BLK;          // second float4 (+4096 floats)
    if (al >= 0 && al + LIN_FLOATS <= T_IN) {
        float4 r0 = *reinterpret_cast<const float4*>(rin + g0);
        float4 r1 = *reinterpret_cast<const float4*>(rin + g1);
        *reinterpret_cast<float4*>(&lin[4 * t])           = r0;
        *reinterpret_cast<float4*>(&lin[4 * (t + BLK)])   = r1;
    } else {
        float r[8];
        #pragma unroll
        for (int c = 0; c < 4; ++c) {
            const int i0 = g0 + c, i1 = g1 + c;
            r[c]     = (i0 >= 0 && i0 < T_IN) ? rin[i0] : 0.f;
            r[4 + c] = (i1 >= 0 && i1 < T_IN) ? rin[i1] : 0.f;
        }
        #pragma unroll
        for (int c = 0; c < 4; ++c) {
            lin[4 * t + c]         = r[c];
            lin[4 * (t + BLK) + c] = r[4 + c];
        }
    }
    __syncthreads();

    // ---- Compute: threads 0..815 each produce one 9-output group.
    if (t < GPB) {
        float v[24];
        const int base = 2 + 10 * t;      // off == 2 always; even -> b64 reads
        #pragma unroll
        for (int m = 0; m < 12; ++m) {
            float2 p = *reinterpret_cast<const float2*>(&lin[base + 2 * m]);
            v[2 * m]     = p.x;
            v[2 * m + 1] = p.y;
        }
        // RB[i] = fi[i] + 6, fi = ceil(i*10/9 - 6.7340067) = {-6..-1,0,2,3}
        constexpr int RB[9] = {0, 1, 2, 3, 4, 5, 6, 8, 9};
        #pragma unroll
        for (int i = 0; i < 9; ++i) {
            float s = 0.f;
            #pragma unroll
            for (int j = 0; j < 14; ++j)
                s = fmaf(args.w[i][j], v[RB[i] + j], s);
            lout[9 * t + i] = s;
        }
    }
    __syncthreads();

    // ---- Coalesced float4 store of the block's contiguous output region.
    const int gcount = min(GPB, K_TOT - k0);          // 816 or 672 (last block)
    const int nq = (gcount * 9) >> 2;                 // both divisible by 4
    float* obase = out + (size_t)row * OUT_PER_ROW + (size_t)k0 * 9;
    for (int q = t; q < nq; q += BLK) {
        *reinterpret_cast<float4*>(obase + 4 * q) =
            *reinterpret_cast<const float4*>(&lout[4 * q]);
    }
}

extern "C" void kernel_launch(void* const* d_in, const int* in_sizes, int n_in,
                              void* d_out, int out_size, void* d_ws, size_t ws_size,
                              hipStream_t stream) {
    const float* in  = (const float*)d_in[0];
    float*       out = (float*)d_out;
    const int B = out_size / OUT_PER_ROW;

    // Kaldi LinearResample weights, float64 math mirroring the reference.
    ResampleW args;
    const double orig = 16000.0;
    const double lowpass_cutoff = 0.99 * 0.5 * 14400.0;     // min_freq = 14400
    const double window_width = 6.0 / (2.0 * lowpass_cutoff);
    const double PI = 3.14159265358979323846;
    for (int i = 0; i < 9; ++i) {
        const double output_t = (double)i / 14400.0;
        const double min_input_index = ceil((output_t - window_width) * orig);
        for (int j = 0; j < 14; ++j) {
            const double delta_t = (min_input_index + j) / orig - output_t;
            double w = 0.0;
            if (fabs(delta_t) < window_width) {
                w = 0.5 * (1.0 + cos(2.0 * PI * lowpass_cutoff / 6.0 * delta_t));
                if (delta_t != 0.0)
                    w *= sin(2.0 * PI * lowpass_cutoff * delta_t) / (PI * delta_t);
                else
                    w *= 2.0 * lowpass_cutoff;
                w /= orig;
            }
            args.w[i][j] = (float)w;
        }
    }

    dim3 grid((K_TOT + GPB - 1) / GPB, B);   // 59 x 64
    SpeedPerturb_resample_kernel<<<grid, dim3(BLK), 0, stream>>>(in, out, args);
}

// Round 6
// 208.185 us; speedup vs baseline: 1.0135x; 1.0135x over previous
//
#include <hip/hip_runtime.h>
#include <math.h>

#define T_IN        480000
#define OUT_PER_ROW 432000
#define K_TOT       48000      // output 9-groups per row
#define BLK         256        // threads per block
#define GROUPS_PB   (2 * BLK)  // 512 k-groups per block (1 k-pair per thread)
#define OUT_LDS     (GROUPS_PB * 9)   // 4608 staged outputs per block

struct ResampleW { float w[9][14]; };

__global__ __launch_bounds__(BLK)
void SpeedPerturb_resample_kernel(const float* __restrict__ in,
                                  float* __restrict__ out,
                                  ResampleW args)
{
    __shared__ float lout[OUT_LDS];
    const int row = blockIdx.y;
    const int k0  = blockIdx.x * GROUPS_PB;
    const int t   = threadIdx.x;
    const int kp  = (k0 >> 1) + t;                // this thread's k-pair
    const float* rin = in + (size_t)row * T_IN;

    // Window for pair kp: input[20*kp-6 .. 20*kp+26]; 16B-aligned base 20*kp-8.
    const int al = 20 * kp - 8;
    float v[36];
    const bool interior = (blockIdx.x > 0) && (blockIdx.x < gridDim.x - 1);
    if (interior) {
        // Issue ALL 9 dwordx4 loads before any consumer: sched_barrier(0)
        // pins them above the FMAs -> ~9 KB per wave in flight (forced MLP).
        float4 r0 = *reinterpret_cast<const float4*>(rin + al);
        float4 r1 = *reinterpret_cast<const float4*>(rin + al + 4);
        float4 r2 = *reinterpret_cast<const float4*>(rin + al + 8);
        float4 r3 = *reinterpret_cast<const float4*>(rin + al + 12);
        float4 r4 = *reinterpret_cast<const float4*>(rin + al + 16);
        float4 r5 = *reinterpret_cast<const float4*>(rin + al + 20);
        float4 r6 = *reinterpret_cast<const float4*>(rin + al + 24);
        float4 r7 = *reinterpret_cast<const float4*>(rin + al + 28);
        float4 r8 = *reinterpret_cast<const float4*>(rin + al + 32);
        __builtin_amdgcn_sched_barrier(0);
        v[0]=r0.x; v[1]=r0.y; v[2]=r0.z; v[3]=r0.w;
        v[4]=r1.x; v[5]=r1.y; v[6]=r1.z; v[7]=r1.w;
        v[8]=r2.x; v[9]=r2.y; v[10]=r2.z; v[11]=r2.w;
        v[12]=r3.x; v[13]=r3.y; v[14]=r3.z; v[15]=r3.w;
        v[16]=r4.x; v[17]=r4.y; v[18]=r4.z; v[19]=r4.w;
        v[20]=r5.x; v[21]=r5.y; v[22]=r5.z; v[23]=r5.w;
        v[24]=r6.x; v[25]=r6.y; v[26]=r6.z; v[27]=r6.w;
        v[28]=r7.x; v[29]=r7.y; v[30]=r7.z; v[31]=r7.w;
        v[32]=r8.x; v[33]=r8.y; v[34]=r8.z; v[35]=r8.w;
    } else {
        #pragma unroll
        for (int m = 0; m < 36; ++m) {
            const int idx = al + m;
            v[m] = (idx >= 0 && idx < T_IN) ? rin[idx] : 0.f;
        }
    }

    // RB[i] = fi[i] + 6, fi = ceil(i*10/9 - 6.7340067) = {-6..-1,0,2,3}
    constexpr int RB[9] = {0, 1, 2, 3, 4, 5, 6, 8, 9};

    #pragma unroll
    for (int g = 0; g < 2; ++g) {
        const int k = k0 + 2 * t + g;
        if (k < K_TOT) {
            #pragma unroll
            for (int i = 0; i < 9; ++i) {
                float s = 0.f;
                #pragma unroll
                for (int j = 0; j < 14; ++j)
                    s = fmaf(args.w[i][j], v[2 + 10 * g + RB[i] + j], s);
                lout[18 * t + 9 * g + i] = s;
            }
        }
    }
    __syncthreads();

    // Coalesced float4 store of the block's contiguous output region.
    const int gcount = min(GROUPS_PB, K_TOT - k0);     // 512 or 384 (last block)
    const int nq = (gcount * 9) >> 2;                  // both divisible by 4
    float* obase = out + (size_t)row * OUT_PER_ROW + (size_t)k0 * 9;
    for (int q = t; q < nq; q += BLK) {
        *reinterpret_cast<float4*>(obase + 4 * q) =
            *reinterpret_cast<const float4*>(&lout[4 * q]);
    }
}

extern "C" void kernel_launch(void* const* d_in, const int* in_sizes, int n_in,
                              void* d_out, int out_size, void* d_ws, size_t ws_size,
                              hipStream_t stream) {
    const float* in  = (const float*)d_in[0];
    float*       out = (float*)d_out;
    const int B = out_size / OUT_PER_ROW;

    // Kaldi LinearResample weights, float64 math mirroring the reference.
    ResampleW args;
    const double orig = 16000.0;
    const double lowpass_cutoff = 0.99 * 0.5 * 14400.0;     // min_freq = 14400
    const double window_width = 6.0 / (2.0 * lowpass_cutoff);
    const double PI = 3.14159265358979323846;
    for (int i = 0; i < 9; ++i) {
        const double output_t = (double)i / 14400.0;
        const double min_input_index = ceil((output_t - window_width) * orig);
        for (int j = 0; j < 14; ++j) {
            const double delta_t = (min_input_index + j) / orig - output_t;
            double w = 0.0;
            if (fabs(delta_t) < window_width) {
                w = 0.5 * (1.0 + cos(2.0 * PI * lowpass_cutoff / 6.0 * delta_t));
                if (delta_t != 0.0)
                    w *= sin(2.0 * PI * lowpass_cutoff * delta_t) / (PI * delta_t);
                else
                    w *= 2.0 * lowpass_cutoff;
                w /= orig;
            }
            args.w[i][j] = (float)w;
        }
    }

    dim3 grid((K_TOT + GROUPS_PB - 1) / GROUPS_PB, B);   // 94 x 64
    SpeedPerturb_resample_kernel<<<grid, dim3(BLK), 0, stream>>>(in, out, args);
}